// Round 13
// baseline (145.233 us; speedup 1.0000x reference)
//
#include <hip/hip_runtime.h>

using u16 = unsigned short;
using uch = unsigned char;

typedef __bf16 bf16x8 __attribute__((ext_vector_type(8)));
typedef float f32x4 __attribute__((ext_vector_type(4)));

// ---------- constants ----------
#define BATCH 4
#define SEQN 4096
#define TT 16
#define MM 64
#define DIM 1024
#define HEADS 8
#define DH 64
#define INNER 512
#define KVN 1024
#define NTOK (BATCH*SEQN)          // 16384
#define MAXBLK 352

// front_kernel role boundaries (256-thread blocks)
#define FB_WT0  1
#define FB_CVT0 2049
#define FB_LN0  6145
#define FB_GRID (FB_LN0 + NTOK)    // 22529

// ws offsets (bytes)
#define OFF_XN     ((size_t)0)                     // 16384x1024 bf16 = 32MB
#define OFF_MEDIA  ((size_t)33554432)              // 4096x1024 bf16 = 8MB
#define OFF_Q      ((size_t)41943040)              // 16384x512 bf16 = 16MB
#define OFF_KV     ((size_t)58720256)              // 4096x1024 bf16 = 8MB
#define OFF_AOUT   ((size_t)67108864)              // 16384x512 bf16 = 16MB
#define OFF_WQT    ((size_t)83886080)              // 512x1024 bf16 = 1MB
#define OFF_WKVT   ((size_t)84934656)              // 1024x1024 bf16 = 2MB
#define OFF_WOT    ((size_t)87031808)              // 1024x512 bf16 = 1MB
#define OFF_VSUM   ((size_t)88145920)              // 4x512 f32 = 8KB
#define OFF_FLAGS  ((size_t)88154112)              // int[2]
#define OFF_VT     ((size_t)88155136)              // 64 groups x 512 x 64 bf16 = 4MB
#define OFF_NBLK   ((size_t)92350464)              // int
#define OFF_DESC   ((size_t)92351488)              // MAXBLK x int4

__device__ __forceinline__ u16 f2bf(float f){
  unsigned int u = __float_as_uint(f);
  u += 0x7fffu + ((u >> 16) & 1u);
  return (u16)(u >> 16);
}
__device__ __forceinline__ float bf2f(u16 b){ return __uint_as_float(((unsigned int)b) << 16); }

__device__ __forceinline__ void async16(const u16* g, void* l){
  __builtin_amdgcn_global_load_lds((__attribute__((address_space(1))) void*)(g),
                                   (__attribute__((address_space(3))) void*)(l), 16, 0, 0);
}

// per-block dtype probe on x[0..1023] words (4KB, valid under fp32 or bf16 layout).
__device__ __forceinline__ int detect_bf16(const unsigned int* __restrict__ x){
  __shared__ int scnt;
  const int tid = threadIdx.x;
  if (tid == 0) scnt = 0;
  __syncthreads();
  int c = 0;
  #pragma unroll
  for (int t = 0; t < 4; ++t){
    unsigned int w = x[t*256 + tid];
    unsigned int e = (w >> 7) & 0xFFu;
    c += (e >= 110u && e <= 140u) ? 1 : 0;
  }
  #pragma unroll
  for (int o = 32; o > 0; o >>= 1) c += __shfl_down(c, o);
  if ((tid & 63) == 0) atomicAdd(&scnt, c);
  __syncthreads();
  return scnt > 512 ? 1 : 0;
}

// ---------- front: prep + weight transposes + LN + media cvt (ONE dispatch) ----------
__global__ __launch_bounds__(256) void front_kernel(
    const unsigned int* __restrict__ x, const uch* __restrict__ loc,
    const void* __restrict__ ln_g, const void* __restrict__ ln_b,
    const void* __restrict__ media,
    const void* __restrict__ Wq, const void* __restrict__ Wk,
    const void* __restrict__ Wv, const void* __restrict__ Wo,
    u16* __restrict__ xn, u16* __restrict__ medb,
    u16* __restrict__ WqT, u16* __restrict__ WkvT, u16* __restrict__ WoT,
    int* __restrict__ flags, float* __restrict__ vsum,
    int4* __restrict__ desc, int* __restrict__ nblk){
  const int bid = blockIdx.x, tid = threadIdx.x;

  if (bid == 0){
    // ---- prep: loc-format probe, vsum zero, cumsum->bounds, plan ----
    __shared__ int nonzS;
    __shared__ int wsumS[4];
    __shared__ int sbound[4][19];
    __shared__ int gcnt[72];
    int bf = detect_bf16(x);
    if (tid == 0) nonzS = 0;
    if (tid < 76) sbound[tid/19][tid%19] = 4096;
    #pragma unroll
    for (int t = 0; t < 8; ++t) vsum[t*256 + tid] = 0.f;
    __syncthreads();
    int nz = 0;
    #pragma unroll
    for (int t = 0; t < 16; ++t){
      int i = t*256 + tid;                 // first 16KB valid in both layouts
      if ((i & 3) && loc[i]) nz++;
    }
    #pragma unroll
    for (int o = 32; o > 0; o >>= 1) nz += __shfl_down(nz, o);
    if ((tid & 63) == 0) atomicAdd(&nonzS, nz);
    __syncthreads();
    const int as32 = (nonzS == 0) ? 1 : 0;
    if (tid == 0){ flags[0] = bf; flags[1] = as32; }
    const int lane = tid & 63, wl = tid >> 6;
    for (int b = 0; b < BATCH; ++b){
      int v[16];
      if (as32){
        const int4* p = (const int4*)((const int*)loc + b*SEQN + tid*16);
        #pragma unroll
        for (int j = 0; j < 4; ++j){
          int4 q = p[j];
          v[j*4+0]=q.x!=0; v[j*4+1]=q.y!=0; v[j*4+2]=q.z!=0; v[j*4+3]=q.w!=0;
        }
      } else {
        const uchar4* p = (const uchar4*)(loc + b*SEQN + tid*16);
        #pragma unroll
        for (int j = 0; j < 4; ++j){
          uchar4 q = p[j];
          v[j*4+0]=q.x!=0; v[j*4+1]=q.y!=0; v[j*4+2]=q.z!=0; v[j*4+3]=q.w!=0;
        }
      }
      int tsum = 0;
      #pragma unroll
      for (int j = 0; j < 16; ++j) tsum += v[j];
      int s = tsum;
      #pragma unroll
      for (int o = 1; o < 64; o <<= 1){ int n2 = __shfl_up(s, o); if (lane >= o) s += n2; }
      if (lane == 63) wsumS[wl] = s;
      __syncthreads();
      int base = 0;
      for (int w2 = 0; w2 < wl; ++w2) base += wsumS[w2];
      int tt = base + s - tsum;            // exclusive prefix before my 16 tokens
      #pragma unroll
      for (int j = 0; j < 16; ++j){
        if (v[j]){ tt++; if (tt <= 17) sbound[b][tt] = tid*16 + j; }
      }
      __syncthreads();
    }
    if (tid < 72){
      int bb = tid/18, g = tid%18;
      int lo = (g == 0) ? 0 : sbound[bb][g];
      int hi = (g < 17) ? sbound[bb][g+1] : 4096;
      if (hi < lo) hi = lo;
      gcnt[tid] = (hi - lo + 63) >> 6;
    }
    __syncthreads();
    if (tid == 0){
      int acc = 0;
      for (int i = 0; i < 72; ++i){ int c2 = gcnt[i]; gcnt[i] = acc; acc += c2; }
      *nblk = acc;
    }
    __syncthreads();
    if (tid < 72){
      int bb = tid/18, g = tid%18;
      int lo = (g == 0) ? 0 : sbound[bb][g];
      int hi = (g < 17) ? sbound[bb][g+1] : 4096;
      if (hi < lo) hi = lo;
      int s2 = (g == 0 || g == 17) ? -1 : (g - 1);
      int n0 = gcnt[tid];
      for (int k = lo, j = 0; k < hi; k += 64, ++j){
        int4 d; d.x = bb; d.y = s2; d.z = bb*4096 + k; d.w = min(64, hi - k);
        desc[n0 + j] = d;
      }
    }
    return;
  }

  if (bid < FB_CVT0){
    // ---- weight transpose: in [K][N] -> out [N][K] bf16 ----
    const int bf = detect_bf16(x);
    __shared__ float tile[32][33];
    int id = bid - FB_WT0;
    const void* in; u16* out; int K, N, bx, by;
    if (id < 512){       in = Wq; out = WqT;  K = DIM;   N = INNER; bx = id & 15; by = id >> 4; }
    else if (id < 1024){ in = Wk; out = WkvT; K = DIM;   N = INNER; int l = id - 512;  bx = l & 15; by = l >> 4; }
    else if (id < 1536){ in = Wv; out = WkvT + (size_t)512*1024; K = DIM; N = INNER; int l = id - 1024; bx = l & 15; by = l >> 4; }
    else {               in = Wo; out = WoT;  K = INNER; N = DIM;   int l = id - 1536; bx = l & 31; by = l >> 5; }
    int n0 = bx*32, k0 = by*32;
    int tx = tid & 31, ty = tid >> 5;
    #pragma unroll
    for (int i = 0; i < 4; ++i){
      size_t idx = (size_t)(k0 + ty + i*8)*N + n0 + tx;
      tile[ty + i*8][tx] = bf ? bf2f(((const u16*)in)[idx]) : ((const float*)in)[idx];
    }
    __syncthreads();
    #pragma unroll
    for (int i = 0; i < 4; ++i)
      out[(size_t)(n0 + ty + i*8)*K + k0 + tx] = f2bf(tile[tx][ty + i*8]);
    return;
  }

  if (bid < FB_LN0){
    // ---- media convert ----
    const int bf = detect_bf16(x);
    size_t i = (size_t)(bid - FB_CVT0)*256 + tid;
    if (bf){
      ((ushort4*)medb)[i] = ((const ushort4*)media)[i];
    } else {
      float4 t = ((const float4*)media)[i];
      ushort4 o; o.x = f2bf(t.x); o.y = f2bf(t.y); o.z = f2bf(t.z); o.w = f2bf(t.w);
      ((ushort4*)medb)[i] = o;
    }
    return;
  }

  // ---- LayerNorm row ----
  const int bf = detect_bf16(x);
  const int row = bid - FB_LN0;
  float v[4];
  if (bf){
    ushort4 t = ((const ushort4*)((const u16*)x + (size_t)row*DIM))[tid];
    v[0]=bf2f(t.x); v[1]=bf2f(t.y); v[2]=bf2f(t.z); v[3]=bf2f(t.w);
  } else {
    float4 t = ((const float4*)((const float*)x + (size_t)row*DIM))[tid];
    v[0]=t.x; v[1]=t.y; v[2]=t.z; v[3]=t.w;
  }
  float s = v[0]+v[1]+v[2]+v[3];
  float sq = v[0]*v[0]+v[1]*v[1]+v[2]*v[2]+v[3]*v[3];
  #pragma unroll
  for (int o = 32; o > 0; o >>= 1){ s += __shfl_down(s, o); sq += __shfl_down(sq, o); }
  __shared__ float ss[4], ssq[4];
  int wid = tid >> 6, lane = tid & 63;
  if (lane == 0){ ss[wid] = s; ssq[wid] = sq; }
  __syncthreads();
  s = ss[0]+ss[1]+ss[2]+ss[3]; sq = ssq[0]+ssq[1]+ssq[2]+ssq[3];
  float mean = s * (1.f/DIM);
  float rstd = rsqrtf(sq * (1.f/DIM) - mean*mean + 1e-5f);
  float g[4], bb[4];
  if (bf){
    ushort4 t1 = ((const ushort4*)ln_g)[tid]; ushort4 t2 = ((const ushort4*)ln_b)[tid];
    g[0]=bf2f(t1.x); g[1]=bf2f(t1.y); g[2]=bf2f(t1.z); g[3]=bf2f(t1.w);
    bb[0]=bf2f(t2.x); bb[1]=bf2f(t2.y); bb[2]=bf2f(t2.z); bb[3]=bf2f(t2.w);
  } else {
    float4 t1 = ((const float4*)ln_g)[tid]; float4 t2 = ((const float4*)ln_b)[tid];
    g[0]=t1.x; g[1]=t1.y; g[2]=t1.z; g[3]=t1.w;
    bb[0]=t2.x; bb[1]=t2.y; bb[2]=t2.z; bb[3]=t2.w;
  }
  ushort4 o;
  o.x = f2bf((v[0]-mean)*rstd*g[0] + bb[0]);
  o.y = f2bf((v[1]-mean)*rstd*g[1] + bb[1]);
  o.z = f2bf((v[2]-mean)*rstd*g[2] + bb[2]);
  o.w = f2bf((v[3]-mean)*rstd*g[3] + bb[3]);
  ((ushort4*)(xn + (size_t)row*DIM))[tid] = o;
}

// ---------- 8-wave 256x256 GEMM body, counted-vmcnt pipeline (T3+T4+T5) ----------
__device__ __forceinline__ void g8_stage256(const u16* __restrict__ src, char* dst, int K, int t,
                                            int tid, int wid){
  #pragma unroll
  for (int i = 0; i < 4; ++i){
    int s_ = i*512 + tid;
    int row_ = s_ >> 3, g_ = s_ & 7;
    async16(src + (size_t)row_*K + t*64 + ((g_ ^ (row_ & 7)) << 3),
            dst + (size_t)(i*512 + wid*64)*16);
  }
}

// MODE 0: C bf16 (alpha applied).  MODE 1: C bf16 if flags[0] else fp32.
// MODE 2: kv epilogue — C bf16 + dual-write V^T + vsum column partials.
template<int NT, int MODE>
__device__ __forceinline__ void gemm8_body(const u16* __restrict__ A, const u16* __restrict__ Bt,
                        void* __restrict__ Cp, int Nglob, float alpha, const int* __restrict__ flags,
                        int rm, int rn, u16* sA0, u16* sA1, u16* sB0, u16* sB1,
                        u16* __restrict__ vtp, float* __restrict__ vsum){
  constexpr int K = NT*64;
  const int tid = threadIdx.x, wid = tid >> 6, lane = tid & 63;
  const int wr = wid >> 2, wc = wid & 3;
  const int lr = lane & 15, lg = lane >> 4;
  f32x4 acc[8][4] = {};
  const u16* Ab = A + (size_t)rm*256*K;
  const u16* Bb = Bt + (size_t)rn*256*K;

  // prologue: issue tile 0 (8 load-instructions/wave: 4 A + 4 B)
  g8_stage256(Ab, (char*)sA0, K, 0, tid, wid);
  g8_stage256(Bb, (char*)sB0, K, 0, tid, wid);

  for (int t = 0; t < NT; ++t){
    u16* Acur = (t & 1) ? sA1 : sA0;
    u16* Bcur = (t & 1) ? sB1 : sB0;
    u16* Anxt = (t & 1) ? sA0 : sA1;
    u16* Bnxt = (t & 1) ? sB0 : sB1;
    // issue next tile, then wait only for CURRENT tile (counted vmcnt):
    // next tile's 8 loads stay in flight across all phase barriers below.
    if (t + 1 < NT){
      g8_stage256(Ab, (char*)Anxt, K, t+1, tid, wid);
      g8_stage256(Bb, (char*)Bnxt, K, t+1, tid, wid);
      asm volatile("s_waitcnt vmcnt(8)" ::: "memory");
    } else {
      asm volatile("s_waitcnt vmcnt(0)" ::: "memory");
    }
    __builtin_amdgcn_s_barrier();          // all waves: tile t resident
    __builtin_amdgcn_sched_barrier(0);     // fence: no ds_read hoists above this
    bf16x8 bfr[4][2];
    #pragma unroll
    for (int p = 0; p < 4; ++p){
      bf16x8 af[2][2];
      #pragma unroll
      for (int i = 0; i < 2; ++i){
        int row = wr*128 + (2*p + i)*16 + lr;
        #pragma unroll
        for (int ks = 0; ks < 2; ++ks){
          int g = (ks*4 + lg) ^ (row & 7);
          af[i][ks] = *(const bf16x8*)((const char*)Acur + row*128 + g*16);
        }
      }
      if (p == 0){
        #pragma unroll
        for (int n = 0; n < 4; ++n){
          int row = wc*64 + n*16 + lr;
          #pragma unroll
          for (int ks = 0; ks < 2; ++ks){
            int g = (ks*4 + lg) ^ (row & 7);
            bfr[n][ks] = *(const bf16x8*)((const char*)Bcur + row*128 + g*16);
          }
        }
      }
      __builtin_amdgcn_s_barrier();
      __builtin_amdgcn_s_setprio(1);
      #pragma unroll
      for (int i = 0; i < 2; ++i)
        #pragma unroll
        for (int n = 0; n < 4; ++n)
          #pragma unroll
          for (int ks = 0; ks < 2; ++ks)
            acc[2*p + i][n] = __builtin_amdgcn_mfma_f32_16x16x32_bf16(af[i][ks], bfr[n][ks], acc[2*p + i][n], 0, 0, 0);
      __builtin_amdgcn_s_setprio(0);
      __builtin_amdgcn_s_barrier();        // p3's barrier gates buf reuse next iter
    }
  }

  if (MODE == 2){
    const int batch = rm >> 2;             // 4 row-tiles of 256 per batch (1024 rows)
    #pragma unroll
    for (int n = 0; n < 4; ++n){
      int col = rn*256 + wc*64 + n*16 + lr;
      float psum = 0.f;
      #pragma unroll
      for (int m = 0; m < 8; ++m){
        int row0 = rm*256 + wr*128 + m*16 + lg*4;
        #pragma unroll
        for (int r = 0; r < 4; ++r){
          float v = acc[m][n][r];
          psum += v;
          int row = row0 + r;
          u16 bv = f2bf(v);
          ((u16*)Cp)[(size_t)row*Nglob + col] = bv;
          if (col >= 512){
            int kvi = row & 1023;
            int s = kvi >> 6, rr = kvi & 63;
            vtp[((size_t)(((row >> 10)*16 + s)*512 + (col - 512)))*64 + rr] = bv;
          }
        }
      }
      if (col >= 512) atomicAdd(&vsum[batch*512 + (col - 512)], psum);
    }
    return;
  }
  const bool obf = (MODE == 0) || (flags[0] != 0);
  #pragma unroll
  for (int m = 0; m < 8; ++m){
    #pragma unroll
    for (int n = 0; n < 4; ++n){
      int row0 = rm*256 + wr*128 + m*16 + lg*4;
      int col  = rn*256 + wc*64 + n*16 + lr;
      #pragma unroll
      for (int r = 0; r < 4; ++r){
        float v = acc[m][n][r] * alpha;
        size_t idx = (size_t)(row0 + r)*Nglob + col;
        if (obf) ((u16*)Cp)[idx] = f2bf(v);
        else     ((float*)Cp)[idx] = v;
      }
    }
  }
}

// ---------- proj: q-proj (blocks 0..127) + kv-proj (blocks 128..191), 256^2 pipelined ----------
__global__ __launch_bounds__(512) void proj_kernel(
    const u16* __restrict__ xn, const u16* __restrict__ WqT, u16* __restrict__ qb,
    const u16* __restrict__ medb, const u16* __restrict__ WkvT, u16* __restrict__ kvb,
    u16* __restrict__ vtp, float* __restrict__ vsum, const int* __restrict__ flags){
  __shared__ u16 As[2][16384];
  __shared__ u16 Bs[2][16384];
  if (blockIdx.x < 128){
    // q = (xn @ Wq) * DH^-0.5 : M=16384 (64 tiles) x N=512 (2 tiles)
    int bid = blockIdx.x;
    int wg = (bid & 7)*16 + (bid >> 3);
    gemm8_body<16, 0>(xn, WqT, qb, INNER, 0.125f, flags, wg >> 1, wg & 1,
                      As[0], As[1], Bs[0], Bs[1], nullptr, nullptr);
  } else {
    // kv = media @ [Wk|Wv] : M=4096 (16 tiles) x N=1024 (4 tiles)
    int bid = blockIdx.x - 128;
    int wg = (bid & 7)*8 + (bid >> 3);
    gemm8_body<16, 2>(medb, WkvT, kvb, 1024, 1.f, flags, wg >> 2, wg & 3,
                      As[0], As[1], Bs[0], Bs[1], vtp, vsum);
  }
}

// ---------- out = aout @ Wo, 256^2 pipelined ----------
__global__ __launch_bounds__(512) void gemm8_out_kernel(const u16* __restrict__ A,
                        const u16* __restrict__ Bt, void* __restrict__ Cp,
                        const int* __restrict__ flags){
  __shared__ u16 As[2][16384];
  __shared__ u16 Bs[2][16384];
  int flat = blockIdx.x + blockIdx.y*gridDim.x;   // grid (4,64)
  int wg = (flat & 7)*32 + (flat >> 3);
  int rn = wg & 3, rm = wg >> 2;
  gemm8_body<8, 1>(A, Bt, Cp, DIM, 1.f, flags, rm, rn, As[0], As[1], Bs[0], Bs[1],
                   nullptr, nullptr);
}

// ---------- grouped masked attention: 1 head per block ----------
__global__ __launch_bounds__(256) void attn2_kernel(
    const u16* __restrict__ qb, const u16* __restrict__ kvb, const u16* __restrict__ vt,
    const int* __restrict__ nblk, const int4* __restrict__ desc,
    const float* __restrict__ vsum, u16* __restrict__ aout){
  __shared__ u16 Ks[64*64];
  __shared__ u16 Vs[64*64];
  __shared__ u16 Ps[4][16*72];
  if (blockIdx.x >= *nblk) return;
  const int4 d = desc[blockIdx.x];
  const int b = d.x, s = d.y, rowStart = d.z, cnt = d.w;
  const int h = blockIdx.y;
  const int tid = threadIdx.x, w = tid >> 6, lane = tid & 63;
  if (s < 0){
    const float inv = 1.f/1024.f;
    for (int idx = tid; idx < cnt*64; idx += 256){
      int slot = idx >> 6, c = h*64 + (idx & 63);
      aout[(size_t)(rowStart + slot)*512 + c] = f2bf(vsum[b*512 + c]*inv);
    }
    return;
  }
  const int lr = lane & 15, lg = lane >> 4;
  const size_t kbase = ((size_t)(b*1024 + s*64))*1024;
  const size_t vbase = ((size_t)(b*16 + s))*512*64;
  const int myslot = w*16 + lr;
  const size_t qrow = (size_t)(rowStart + min(myslot, cnt - 1))*512;
  #pragma unroll
  for (int t = 0; t < 2; ++t){
    int ci = t*256 + tid;
    int r = ci >> 3, q = ci & 7;
    int qs = (q ^ (r & 7)) << 3;
    async16(kvb + kbase + (size_t)r*1024 + h*64 + qs, (char*)Ks + ci*16);
    async16(vt + vbase + (size_t)(h*64 + r)*64 + qs, (char*)Vs + ci*16);
  }
  __syncthreads();
  bf16x8 qa0 = *(const bf16x8*)(qb + qrow + h*64 + lg*8);
  bf16x8 qa1 = *(const bf16x8*)(qb + qrow + h*64 + 32 + lg*8);
  f32x4 sv[4] = {};
  #pragma unroll
  for (int n = 0; n < 4; ++n){
    int row = n*16 + lr;
    int sl0 = (lg) ^ (row & 7);
    int sl1 = (4 + lg) ^ (row & 7);
    bf16x8 kb0 = *(const bf16x8*)((const char*)Ks + row*128 + sl0*16);
    sv[n] = __builtin_amdgcn_mfma_f32_16x16x32_bf16(qa0, kb0, sv[n], 0, 0, 0);
    bf16x8 kb1 = *(const bf16x8*)((const char*)Ks + row*128 + sl1*16);
    sv[n] = __builtin_amdgcn_mfma_f32_16x16x32_bf16(qa1, kb1, sv[n], 0, 0, 0);
  }
  float inv[4];
  #pragma unroll
  for (int r = 0; r < 4; ++r){
    float m = fmaxf(fmaxf(sv[0][r], sv[1][r]), fmaxf(sv[2][r], sv[3][r]));
    #pragma unroll
    for (int o = 1; o < 16; o <<= 1) m = fmaxf(m, __shfl_xor(m, o));
    float s0 = 0.f;
    #pragma unroll
    for (int n = 0; n < 4; ++n){ sv[n][r] = __expf(sv[n][r] - m); s0 += sv[n][r]; }
    #pragma unroll
    for (int o = 1; o < 16; o <<= 1) s0 += __shfl_xor(s0, o);
    inv[r] = 1.f / s0;
  }
  u16* pw = &Ps[w][0];
  #pragma unroll
  for (int n = 0; n < 4; ++n)
    #pragma unroll
    for (int r = 0; r < 4; ++r)
      pw[(4*lg + r)*72 + n*16 + lr] = f2bf(sv[n][r] * inv[r]);
  bf16x8 pa0 = *(const bf16x8*)((const char*)pw + lr*144 + lg*16);
  bf16x8 pa1 = *(const bf16x8*)((const char*)pw + lr*144 + 64 + lg*16);
  f32x4 ov[4] = {};
  #pragma unroll
  for (int n = 0; n < 4; ++n){
    int row = n*16 + lr;
    int sl0 = (lg) ^ (row & 7);
    int sl1 = (4 + lg) ^ (row & 7);
    bf16x8 vb0 = *(const bf16x8*)((const char*)Vs + row*128 + sl0*16);
    ov[n] = __builtin_amdgcn_mfma_f32_16x16x32_bf16(pa0, vb0, ov[n], 0, 0, 0);
    bf16x8 vb1 = *(const bf16x8*)((const char*)Vs + row*128 + sl1*16);
    ov[n] = __builtin_amdgcn_mfma_f32_16x16x32_bf16(pa1, vb1, ov[n], 0, 0, 0);
  }
  #pragma unroll
  for (int r = 0; r < 4; ++r){
    int slot = w*16 + 4*lg + r;
    if (slot < cnt){
      size_t orow = (size_t)(rowStart + slot)*512 + h*64;
      #pragma unroll
      for (int n = 0; n < 4; ++n)
        aout[orow + n*16 + lr] = f2bf(ov[n][r]);
    }
  }
}

extern "C" void kernel_launch(void* const* d_in, const int* in_sizes, int n_in,
                              void* d_out, int out_size, void* d_ws, size_t ws_size,
                              hipStream_t stream){
  const void* x      = d_in[0];
  const void* media  = d_in[1];
  const void* mloc   = d_in[2];
  const void* ln_g   = d_in[3];
  const void* ln_b   = d_in[4];
  const void* Wq     = d_in[5];
  const void* Wk     = d_in[6];
  const void* Wv     = d_in[7];
  const void* Wo     = d_in[8];
  char* ws = (char*)d_ws;
  u16* xn    = (u16*)(ws + OFF_XN);
  u16* medb  = (u16*)(ws + OFF_MEDIA);
  u16* qb    = (u16*)(ws + OFF_Q);
  u16* kvb   = (u16*)(ws + OFF_KV);
  u16* aout  = (u16*)(ws + OFF_AOUT);
  u16* WqT   = (u16*)(ws + OFF_WQT);
  u16* WkvT  = (u16*)(ws + OFF_WKVT);
  u16* WoT   = (u16*)(ws + OFF_WOT);
  float* vsm = (float*)(ws + OFF_VSUM);
  int* flags = (int*)(ws + OFF_FLAGS);
  u16* vt    = (u16*)(ws + OFF_VT);
  int* nblk  = (int*)(ws + OFF_NBLK);
  int4* desc = (int4*)(ws + OFF_DESC);

  // 1) prep + weight transposes + LN + media cvt
  front_kernel<<<FB_GRID, 256, 0, stream>>>(
      (const unsigned int*)x, (const uch*)mloc, ln_g, ln_b, media,
      Wq, Wk, Wv, Wo, xn, medb, WqT, WkvT, WoT, flags, vsm, desc, nblk);

  // 2) q-proj + kv-proj, 256^2 counted-vmcnt pipeline, 192 blocks (single round)
  proj_kernel<<<192, 512, 0, stream>>>(xn, WqT, qb, medb, WkvT, kvb, vt, vsm, flags);

  // 3) grouped masked attention
  attn2_kernel<<<dim3(MAXBLK, 8), 256, 0, stream>>>(qb, kvb, vt, nblk, desc, vsm, aout);

  // 4) out-proj (256^2 counted-vmcnt pipeline)
  gemm8_out_kernel<<<dim3(4, 64), 512, 0, stream>>>(aout, WoT, d_out, flags);
}

// Round 16
// 119.693 us; speedup vs baseline: 1.2134x; 1.2134x over previous
//
#include <hip/hip_runtime.h>

using u16 = unsigned short;
using uch = unsigned char;

typedef __bf16 bf16x8 __attribute__((ext_vector_type(8)));
typedef float f32x4 __attribute__((ext_vector_type(4)));

// ---------- constants ----------
#define BATCH 4
#define SEQN 4096
#define TT 16
#define MM 64
#define DIM 1024
#define HEADS 8
#define DH 64
#define INNER 512
#define KVN 1024
#define NTOK (BATCH*SEQN)          // 16384
#define MAXBLK 352

// front_kernel role boundaries (256-thread blocks)
#define FB_WT0  1
#define FB_CVT0 2049
#define FB_LN0  6145
#define FB_GRID (FB_LN0 + NTOK)    // 22529

// ws offsets (bytes)
#define OFF_XN     ((size_t)0)                     // 16384x1024 bf16 = 32MB
#define OFF_MEDIA  ((size_t)33554432)              // 4096x1024 bf16 = 8MB
#define OFF_Q      ((size_t)41943040)              // 16384x512 bf16 = 16MB
#define OFF_KV     ((size_t)58720256)              // 4096x1024 bf16 = 8MB
#define OFF_AOUT   ((size_t)67108864)              // 16384x512 bf16 = 16MB
#define OFF_WQT    ((size_t)83886080)              // 512x1024 bf16 = 1MB
#define OFF_WKVT   ((size_t)84934656)              // 1024x1024 bf16 = 2MB
#define OFF_WOT    ((size_t)87031808)              // 1024x512 bf16 = 1MB
#define OFF_VSUM   ((size_t)88145920)              // 4x512 f32 = 8KB
#define OFF_FLAGS  ((size_t)88154112)              // int[2]
#define OFF_VT     ((size_t)88155136)              // 64 groups x 512 x 64 bf16 = 4MB
#define OFF_NBLK   ((size_t)92350464)              // int
#define OFF_DESC   ((size_t)92351488)              // MAXBLK x int4

__device__ __forceinline__ u16 f2bf(float f){
  unsigned int u = __float_as_uint(f);
  u += 0x7fffu + ((u >> 16) & 1u);
  return (u16)(u >> 16);
}
__device__ __forceinline__ float bf2f(u16 b){ return __uint_as_float(((unsigned int)b) << 16); }

__device__ __forceinline__ void async16(const u16* g, void* l){
  __builtin_amdgcn_global_load_lds((__attribute__((address_space(1))) void*)(g),
                                   (__attribute__((address_space(3))) void*)(l), 16, 0, 0);
}

// per-block dtype probe on x[0..1023] words (4KB, valid under fp32 or bf16 layout).
__device__ __forceinline__ int detect_bf16(const unsigned int* __restrict__ x){
  __shared__ int scnt;
  const int tid = threadIdx.x;
  if (tid == 0) scnt = 0;
  __syncthreads();
  int c = 0;
  #pragma unroll
  for (int t = 0; t < 4; ++t){
    unsigned int w = x[t*256 + tid];
    unsigned int e = (w >> 7) & 0xFFu;
    c += (e >= 110u && e <= 140u) ? 1 : 0;
  }
  #pragma unroll
  for (int o = 32; o > 0; o >>= 1) c += __shfl_down(c, o);
  if ((tid & 63) == 0) atomicAdd(&scnt, c);
  __syncthreads();
  return scnt > 512 ? 1 : 0;
}

// ---------- front: prep + weight transposes + LN + media cvt (ONE dispatch) ----------
__global__ __launch_bounds__(256) void front_kernel(
    const unsigned int* __restrict__ x, const uch* __restrict__ loc,
    const void* __restrict__ ln_g, const void* __restrict__ ln_b,
    const void* __restrict__ media,
    const void* __restrict__ Wq, const void* __restrict__ Wk,
    const void* __restrict__ Wv, const void* __restrict__ Wo,
    u16* __restrict__ xn, u16* __restrict__ medb,
    u16* __restrict__ WqT, u16* __restrict__ WkvT, u16* __restrict__ WoT,
    int* __restrict__ flags, float* __restrict__ vsum,
    int4* __restrict__ desc, int* __restrict__ nblk){
  const int bid = blockIdx.x, tid = threadIdx.x;

  if (bid == 0){
    // ---- prep: loc-format probe, vsum zero, cumsum->bounds, plan ----
    __shared__ int nonzS;
    __shared__ int wsumS[4];
    __shared__ int sbound[4][19];
    __shared__ int gcnt[72];
    int bf = detect_bf16(x);
    if (tid == 0) nonzS = 0;
    if (tid < 76) sbound[tid/19][tid%19] = 4096;
    #pragma unroll
    for (int t = 0; t < 8; ++t) vsum[t*256 + tid] = 0.f;
    __syncthreads();
    int nz = 0;
    #pragma unroll
    for (int t = 0; t < 16; ++t){
      int i = t*256 + tid;                 // first 16KB valid in both layouts
      if ((i & 3) && loc[i]) nz++;
    }
    #pragma unroll
    for (int o = 32; o > 0; o >>= 1) nz += __shfl_down(nz, o);
    if ((tid & 63) == 0) atomicAdd(&nonzS, nz);
    __syncthreads();
    const int as32 = (nonzS == 0) ? 1 : 0;
    if (tid == 0){ flags[0] = bf; flags[1] = as32; }
    const int lane = tid & 63, wl = tid >> 6;
    for (int b = 0; b < BATCH; ++b){
      int v[16];
      if (as32){
        const int4* p = (const int4*)((const int*)loc + b*SEQN + tid*16);
        #pragma unroll
        for (int j = 0; j < 4; ++j){
          int4 q = p[j];
          v[j*4+0]=q.x!=0; v[j*4+1]=q.y!=0; v[j*4+2]=q.z!=0; v[j*4+3]=q.w!=0;
        }
      } else {
        const uchar4* p = (const uchar4*)(loc + b*SEQN + tid*16);
        #pragma unroll
        for (int j = 0; j < 4; ++j){
          uchar4 q = p[j];
          v[j*4+0]=q.x!=0; v[j*4+1]=q.y!=0; v[j*4+2]=q.z!=0; v[j*4+3]=q.w!=0;
        }
      }
      int tsum = 0;
      #pragma unroll
      for (int j = 0; j < 16; ++j) tsum += v[j];
      int s = tsum;
      #pragma unroll
      for (int o = 1; o < 64; o <<= 1){ int n2 = __shfl_up(s, o); if (lane >= o) s += n2; }
      if (lane == 63) wsumS[wl] = s;
      __syncthreads();
      int base = 0;
      for (int w2 = 0; w2 < wl; ++w2) base += wsumS[w2];
      int tt = base + s - tsum;            // exclusive prefix before my 16 tokens
      #pragma unroll
      for (int j = 0; j < 16; ++j){
        if (v[j]){ tt++; if (tt <= 17) sbound[b][tt] = tid*16 + j; }
      }
      __syncthreads();
    }
    if (tid < 72){
      int bb = tid/18, g = tid%18;
      int lo = (g == 0) ? 0 : sbound[bb][g];
      int hi = (g < 17) ? sbound[bb][g+1] : 4096;
      if (hi < lo) hi = lo;
      gcnt[tid] = (hi - lo + 63) >> 6;
    }
    __syncthreads();
    if (tid == 0){
      int acc = 0;
      for (int i = 0; i < 72; ++i){ int c2 = gcnt[i]; gcnt[i] = acc; acc += c2; }
      *nblk = acc;
    }
    __syncthreads();
    if (tid < 72){
      int bb = tid/18, g = tid%18;
      int lo = (g == 0) ? 0 : sbound[bb][g];
      int hi = (g < 17) ? sbound[bb][g+1] : 4096;
      if (hi < lo) hi = lo;
      int s2 = (g == 0 || g == 17) ? -1 : (g - 1);
      int n0 = gcnt[tid];
      for (int k = lo, j = 0; k < hi; k += 64, ++j){
        int4 d; d.x = bb; d.y = s2; d.z = bb*4096 + k; d.w = min(64, hi - k);
        desc[n0 + j] = d;
      }
    }
    return;
  }

  if (bid < FB_CVT0){
    // ---- weight transpose: in [K][N] -> out [N][K] bf16 ----
    const int bf = detect_bf16(x);
    __shared__ float tile[32][33];
    int id = bid - FB_WT0;
    const void* in; u16* out; int K, N, bx, by;
    if (id < 512){       in = Wq; out = WqT;  K = DIM;   N = INNER; bx = id & 15; by = id >> 4; }
    else if (id < 1024){ in = Wk; out = WkvT; K = DIM;   N = INNER; int l = id - 512;  bx = l & 15; by = l >> 4; }
    else if (id < 1536){ in = Wv; out = WkvT + (size_t)512*1024; K = DIM; N = INNER; int l = id - 1024; bx = l & 15; by = l >> 4; }
    else {               in = Wo; out = WoT;  K = INNER; N = DIM;   int l = id - 1536; bx = l & 31; by = l >> 5; }
    int n0 = bx*32, k0 = by*32;
    int tx = tid & 31, ty = tid >> 5;
    #pragma unroll
    for (int i = 0; i < 4; ++i){
      size_t idx = (size_t)(k0 + ty + i*8)*N + n0 + tx;
      tile[ty + i*8][tx] = bf ? bf2f(((const u16*)in)[idx]) : ((const float*)in)[idx];
    }
    __syncthreads();
    #pragma unroll
    for (int i = 0; i < 4; ++i)
      out[(size_t)(n0 + ty + i*8)*K + k0 + tx] = f2bf(tile[tx][ty + i*8]);
    return;
  }

  if (bid < FB_LN0){
    // ---- media convert ----
    const int bf = detect_bf16(x);
    size_t i = (size_t)(bid - FB_CVT0)*256 + tid;
    if (bf){
      ((ushort4*)medb)[i] = ((const ushort4*)media)[i];
    } else {
      float4 t = ((const float4*)media)[i];
      ushort4 o; o.x = f2bf(t.x); o.y = f2bf(t.y); o.z = f2bf(t.z); o.w = f2bf(t.w);
      ((ushort4*)medb)[i] = o;
    }
    return;
  }

  // ---- LayerNorm row ----
  const int bf = detect_bf16(x);
  const int row = bid - FB_LN0;
  float v[4];
  if (bf){
    ushort4 t = ((const ushort4*)((const u16*)x + (size_t)row*DIM))[tid];
    v[0]=bf2f(t.x); v[1]=bf2f(t.y); v[2]=bf2f(t.z); v[3]=bf2f(t.w);
  } else {
    float4 t = ((const float4*)((const float*)x + (size_t)row*DIM))[tid];
    v[0]=t.x; v[1]=t.y; v[2]=t.z; v[3]=t.w;
  }
  float s = v[0]+v[1]+v[2]+v[3];
  float sq = v[0]*v[0]+v[1]*v[1]+v[2]*v[2]+v[3]*v[3];
  #pragma unroll
  for (int o = 32; o > 0; o >>= 1){ s += __shfl_down(s, o); sq += __shfl_down(sq, o); }
  __shared__ float ss[4], ssq[4];
  int wid = tid >> 6, lane = tid & 63;
  if (lane == 0){ ss[wid] = s; ssq[wid] = sq; }
  __syncthreads();
  s = ss[0]+ss[1]+ss[2]+ss[3]; sq = ssq[0]+ssq[1]+ssq[2]+ssq[3];
  float mean = s * (1.f/DIM);
  float rstd = rsqrtf(sq * (1.f/DIM) - mean*mean + 1e-5f);
  float g[4], bb[4];
  if (bf){
    ushort4 t1 = ((const ushort4*)ln_g)[tid]; ushort4 t2 = ((const ushort4*)ln_b)[tid];
    g[0]=bf2f(t1.x); g[1]=bf2f(t1.y); g[2]=bf2f(t1.z); g[3]=bf2f(t1.w);
    bb[0]=bf2f(t2.x); bb[1]=bf2f(t2.y); bb[2]=bf2f(t2.z); bb[3]=bf2f(t2.w);
  } else {
    float4 t1 = ((const float4*)ln_g)[tid]; float4 t2 = ((const float4*)ln_b)[tid];
    g[0]=t1.x; g[1]=t1.y; g[2]=t1.z; g[3]=t1.w;
    bb[0]=t2.x; bb[1]=t2.y; bb[2]=t2.z; bb[3]=t2.w;
  }
  ushort4 o;
  o.x = f2bf((v[0]-mean)*rstd*g[0] + bb[0]);
  o.y = f2bf((v[1]-mean)*rstd*g[1] + bb[1]);
  o.z = f2bf((v[2]-mean)*rstd*g[2] + bb[2]);
  o.w = f2bf((v[3]-mean)*rstd*g[3] + bb[3]);
  ((ushort4*)(xn + (size_t)row*DIM))[tid] = o;
}

// ---------- 128^2 dbuf GEMM body with COUNTED vmcnt (T4): waits only current tile ----------
__device__ __forceinline__ void stage128(const u16* __restrict__ Ab, const u16* __restrict__ Bb,
                                         int K, int k0, u16* As, u16* Bs, int tid, int wid){
  #pragma unroll
  for (int t = 0; t < 4; ++t){
    int c = t*256 + tid;
    int row = c >> 3;
    int qs = (c & 7) ^ (row & 7);
    int ldsOff = (t*256 + wid*64) * 16;
    async16(Ab + (size_t)row*K + k0 + qs*8, (char*)As + ldsOff);
    async16(Bb + (size_t)row*K + k0 + qs*8, (char*)Bs + ldsOff);
  }
}

// MODE 0: C bf16 (alpha).  MODE 1: C bf16 if flags[0] else fp32.  MODE 2: kv epilogue.
template<int MODE>
__device__ __forceinline__ void gemm128_body(const u16* __restrict__ A, const u16* __restrict__ Bt,
                        void* __restrict__ Cp, int Nglob, int K, float alpha, int rm, int rn,
                        u16* As0, u16* As1, u16* Bs0, u16* Bs1,
                        u16* __restrict__ vtp, float* __restrict__ vsum,
                        const int* __restrict__ flags){
  const int tid = threadIdx.x, wid = tid >> 6, lane = tid & 63;
  const int wr = wid >> 1, wc = wid & 1;
  const int lr = lane & 15, lg = lane >> 4;
  f32x4 acc[4][4] = {};
  const u16* Ab = A + (size_t)rm*128*K;
  const u16* Bb = Bt + (size_t)rn*128*K;
  const int NT = K >> 6;

  stage128(Ab, Bb, K, 0, As0, Bs0, tid, wid);      // 8 loads/thread in flight
  for (int t = 0; t < NT; ++t){
    u16* Ac = (t & 1) ? As1 : As0;
    u16* Bc = (t & 1) ? Bs1 : Bs0;
    u16* An = (t & 1) ? As0 : As1;
    u16* Bn = (t & 1) ? Bs0 : Bs1;
    if (t + 1 < NT){
      // issue next tile (other buffer — freed by PREVIOUS iter's trailing barrier),
      // then wait ONLY for the current tile's 8 loads; next tile's stay in flight.
      stage128(Ab, Bb, K, (t+1)*64, An, Bn, tid, wid);
      asm volatile("s_waitcnt vmcnt(8)" ::: "memory");
    } else {
      asm volatile("s_waitcnt vmcnt(0)" ::: "memory");
    }
    __builtin_amdgcn_s_barrier();                  // tile t resident for all waves
    __builtin_amdgcn_sched_barrier(0);             // no ds_read hoists above the wait
    #pragma unroll
    for (int ks = 0; ks < 2; ++ks){
      bf16x8 af[4], bfr[4];
      #pragma unroll
      for (int m = 0; m < 4; ++m){
        int row = wr*64 + m*16 + lr;
        int q = (ks*4 + lg) ^ (row & 7);
        af[m] = *(const bf16x8*)((const char*)Ac + row*128 + (q << 4));
      }
      #pragma unroll
      for (int n = 0; n < 4; ++n){
        int row = wc*64 + n*16 + lr;
        int q = (ks*4 + lg) ^ (row & 7);
        bfr[n] = *(const bf16x8*)((const char*)Bc + row*128 + (q << 4));
      }
      #pragma unroll
      for (int m = 0; m < 4; ++m)
        #pragma unroll
        for (int n = 0; n < 4; ++n)
          acc[m][n] = __builtin_amdgcn_mfma_f32_16x16x32_bf16(af[m], bfr[n], acc[m][n], 0, 0, 0);
    }
    __builtin_amdgcn_s_barrier();                  // all waves done reading cur buf
  }
  if (MODE == 2){
    const int batch = rm >> 3;             // 8 row-tiles of 128 per batch (1024 rows)
    #pragma unroll
    for (int n = 0; n < 4; ++n){
      int col = rn*128 + wc*64 + n*16 + lr;
      float psum = 0.f;
      #pragma unroll
      for (int m = 0; m < 4; ++m){
        int row0 = rm*128 + wr*64 + m*16 + lg*4;
        #pragma unroll
        for (int r = 0; r < 4; ++r){
          float v = acc[m][n][r];
          psum += v;
          int row = row0 + r;
          u16 bv = f2bf(v);
          ((u16*)Cp)[(size_t)row*Nglob + col] = bv;
          if (col >= 512){
            int kvi = row & 1023;
            int s = kvi >> 6, rr = kvi & 63;
            vtp[((size_t)(((row >> 10)*16 + s)*512 + (col - 512)))*64 + rr] = bv;
          }
        }
      }
      if (col >= 512) atomicAdd(&vsum[batch*512 + (col - 512)], psum);
    }
  } else if (MODE == 1){
    const bool obf = flags[0] != 0;
    #pragma unroll
    for (int m = 0; m < 4; ++m){
      #pragma unroll
      for (int n = 0; n < 4; ++n){
        int row0 = rm*128 + wr*64 + m*16 + lg*4;
        int col  = rn*128 + wc*64 + n*16 + lr;
        #pragma unroll
        for (int r = 0; r < 4; ++r){
          float v = acc[m][n][r];
          size_t idx = (size_t)(row0 + r)*Nglob + col;
          if (obf) ((u16*)Cp)[idx] = f2bf(v);
          else     ((float*)Cp)[idx] = v;
        }
      }
    }
  } else {
    #pragma unroll
    for (int m = 0; m < 4; ++m){
      #pragma unroll
      for (int n = 0; n < 4; ++n){
        int row0 = rm*128 + wr*64 + m*16 + lg*4;
        int col  = rn*128 + wc*64 + n*16 + lr;
        #pragma unroll
        for (int r = 0; r < 4; ++r)
          ((u16*)Cp)[(size_t)(row0 + r)*Nglob + col] = f2bf(acc[m][n][r] * alpha);
      }
    }
  }
}

// ---------- proj: q-proj (blocks 0..511) + kv-proj (blocks 512..767) ----------
__global__ __launch_bounds__(256) void proj_kernel(
    const u16* __restrict__ xn, const u16* __restrict__ WqT, u16* __restrict__ qb,
    const u16* __restrict__ medb, const u16* __restrict__ WkvT, u16* __restrict__ kvb,
    u16* __restrict__ vtp, float* __restrict__ vsum){
  __shared__ u16 As[2][128*64];
  __shared__ u16 Bs[2][128*64];
  if (blockIdx.x < 512){
    // q = (xn @ Wq) * DH^-0.5 : M=16384 (128 tiles) x N=512 (4 tiles)
    int bid = blockIdx.x;
    int wg = (bid & 7)*64 + (bid >> 3);
    gemm128_body<0>(xn, WqT, qb, INNER, DIM, 0.125f, wg >> 2, wg & 3,
                    As[0], As[1], Bs[0], Bs[1], nullptr, nullptr, nullptr);
  } else {
    // kv = media @ [Wk|Wv] : M=4096 (32 tiles) x N=1024 (8 tiles)
    int bid = blockIdx.x - 512;
    int wg = (bid & 7)*32 + (bid >> 3);
    gemm128_body<2>(medb, WkvT, kvb, 1024, DIM, 1.f, wg >> 3, wg & 7,
                    As[0], As[1], Bs[0], Bs[1], vtp, vsum, nullptr);
  }
}

// ---------- out = aout @ Wo : M=16384 (128 tiles) x N=1024 (8 tiles), K=512 ----------
__global__ __launch_bounds__(256) void gemm_out_kernel(const u16* __restrict__ A,
                        const u16* __restrict__ Bt, void* __restrict__ Cp,
                        const int* __restrict__ flags){
  __shared__ u16 As[2][128*64];
  __shared__ u16 Bs[2][128*64];
  int bid = blockIdx.x;
  int wg = (bid & 7)*128 + (bid >> 3);
  gemm128_body<1>(A, Bt, Cp, DIM, INNER, 1.f, wg >> 3, wg & 7,
                  As[0], As[1], Bs[0], Bs[1], nullptr, nullptr, flags);
}

// ---------- grouped masked attention: 1 head per block ----------
__global__ __launch_bounds__(256) void attn2_kernel(
    const u16* __restrict__ qb, const u16* __restrict__ kvb, const u16* __restrict__ vt,
    const int* __restrict__ nblk, const int4* __restrict__ desc,
    const float* __restrict__ vsum, u16* __restrict__ aout){
  __shared__ u16 Ks[64*64];
  __shared__ u16 Vs[64*64];
  __shared__ u16 Ps[4][16*72];
  if (blockIdx.x >= *nblk) return;
  const int4 d = desc[blockIdx.x];
  const int b = d.x, s = d.y, rowStart = d.z, cnt = d.w;
  const int h = blockIdx.y;
  const int tid = threadIdx.x, w = tid >> 6, lane = tid & 63;
  if (s < 0){
    const float inv = 1.f/1024.f;
    for (int idx = tid; idx < cnt*64; idx += 256){
      int slot = idx >> 6, c = h*64 + (idx & 63);
      aout[(size_t)(rowStart + slot)*512 + c] = f2bf(vsum[b*512 + c]*inv);
    }
    return;
  }
  const int lr = lane & 15, lg = lane >> 4;
  const size_t kbase = ((size_t)(b*1024 + s*64))*1024;
  const size_t vbase = ((size_t)(b*16 + s))*512*64;
  const int myslot = w*16 + lr;
  const size_t qrow = (size_t)(rowStart + min(myslot, cnt - 1))*512;
  #pragma unroll
  for (int t = 0; t < 2; ++t){
    int ci = t*256 + tid;
    int r = ci >> 3, q = ci & 7;
    int qs = (q ^ (r & 7)) << 3;
    async16(kvb + kbase + (size_t)r*1024 + h*64 + qs, (char*)Ks + ci*16);
    async16(vt + vbase + (size_t)(h*64 + r)*64 + qs, (char*)Vs + ci*16);
  }
  __syncthreads();
  bf16x8 qa0 = *(const bf16x8*)(qb + qrow + h*64 + lg*8);
  bf16x8 qa1 = *(const bf16x8*)(qb + qrow + h*64 + 32 + lg*8);
  f32x4 sv[4] = {};
  #pragma unroll
  for (int n = 0; n < 4; ++n){
    int row = n*16 + lr;
    int sl0 = (lg) ^ (row & 7);
    int sl1 = (4 + lg) ^ (row & 7);
    bf16x8 kb0 = *(const bf16x8*)((const char*)Ks + row*128 + sl0*16);
    sv[n] = __builtin_amdgcn_mfma_f32_16x16x32_bf16(qa0, kb0, sv[n], 0, 0, 0);
    bf16x8 kb1 = *(const bf16x8*)((const char*)Ks + row*128 + sl1*16);
    sv[n] = __builtin_amdgcn_mfma_f32_16x16x32_bf16(qa1, kb1, sv[n], 0, 0, 0);
  }
  float inv[4];
  #pragma unroll
  for (int r = 0; r < 4; ++r){
    float m = fmaxf(fmaxf(sv[0][r], sv[1][r]), fmaxf(sv[2][r], sv[3][r]));
    #pragma unroll
    for (int o = 1; o < 16; o <<= 1) m = fmaxf(m, __shfl_xor(m, o));
    float s0 = 0.f;
    #pragma unroll
    for (int n = 0; n < 4; ++n){ sv[n][r] = __expf(sv[n][r] - m); s0 += sv[n][r]; }
    #pragma unroll
    for (int o = 1; o < 16; o <<= 1) s0 += __shfl_xor(s0, o);
    inv[r] = 1.f / s0;
  }
  u16* pw = &Ps[w][0];
  #pragma unroll
  for (int n = 0; n < 4; ++n)
    #pragma unroll
    for (int r = 0; r < 4; ++r)
      pw[(4*lg + r)*72 + n*16 + lr] = f2bf(sv[n][r] * inv[r]);
  bf16x8 pa0 = *(const bf16x8*)((const char*)pw + lr*144 + lg*16);
  bf16x8 pa1 = *(const bf16x8*)((const char*)pw + lr*144 + 64 + lg*16);
  f32x4 ov[4] = {};
  #pragma unroll
  for (int n = 0; n < 4; ++n){
    int row = n*16 + lr;
    int sl0 = (lg) ^ (row & 7);
    int sl1 = (4 + lg) ^ (row & 7);
    bf16x8 vb0 = *(const bf16x8*)((const char*)Vs + row*128 + sl0*16);
    ov[n] = __builtin_amdgcn_mfma_f32_16x16x32_bf16(pa0, vb0, ov[n], 0, 0, 0);
    bf16x8 vb1 = *(const bf16x8*)((const char*)Vs + row*128 + sl1*16);
    ov[n] = __builtin_amdgcn_mfma_f32_16x16x32_bf16(pa1, vb1, ov[n], 0, 0, 0);
  }
  #pragma unroll
  for (int r = 0; r < 4; ++r){
    int slot = w*16 + 4*lg + r;
    if (slot < cnt){
      size_t orow = (size_t)(rowStart + slot)*512 + h*64;
      #pragma unroll
      for (int n = 0; n < 4; ++n)
        aout[orow + n*16 + lr] = f2bf(ov[n][r]);
    }
  }
}

extern "C" void kernel_launch(void* const* d_in, const int* in_sizes, int n_in,
                              void* d_out, int out_size, void* d_ws, size_t ws_size,
                              hipStream_t stream){
  const void* x      = d_in[0];
  const void* media  = d_in[1];
  const void* mloc   = d_in[2];
  const void* ln_g   = d_in[3];
  const void* ln_b   = d_in[4];
  const void* Wq     = d_in[5];
  const void* Wk     = d_in[6];
  const void* Wv     = d_in[7];
  const void* Wo     = d_in[8];
  char* ws = (char*)d_ws;
  u16* xn    = (u16*)(ws + OFF_XN);
  u16* medb  = (u16*)(ws + OFF_MEDIA);
  u16* qb    = (u16*)(ws + OFF_Q);
  u16* kvb   = (u16*)(ws + OFF_KV);
  u16* aout  = (u16*)(ws + OFF_AOUT);
  u16* WqT   = (u16*)(ws + OFF_WQT);
  u16* WkvT  = (u16*)(ws + OFF_WKVT);
  u16* WoT   = (u16*)(ws + OFF_WOT);
  float* vsm = (float*)(ws + OFF_VSUM);
  int* flags = (int*)(ws + OFF_FLAGS);
  u16* vt    = (u16*)(ws + OFF_VT);
  int* nblk  = (int*)(ws + OFF_NBLK);
  int4* desc = (int4*)(ws + OFF_DESC);

  // 1) prep + weight transposes + LN + media cvt
  front_kernel<<<FB_GRID, 256, 0, stream>>>(
      (const unsigned int*)x, (const uch*)mloc, ln_g, ln_b, media,
      Wq, Wk, Wv, Wo, xn, medb, WqT, WkvT, WoT, flags, vsm, desc, nblk);

  // 2) q-proj + kv-proj, 128^2 dbuf + counted vmcnt, 768 blocks
  proj_kernel<<<768, 256, 0, stream>>>(xn, WqT, qb, medb, WkvT, kvb, vt, vsm);

  // 3) grouped masked attention
  attn2_kernel<<<dim3(MAXBLK, 8), 256, 0, stream>>>(qb, kvb, vt, nblk, desc, vsm, aout);

  // 4) out-proj, same counted-vmcnt body, 1024 blocks
  gemm_out_kernel<<<1024, 256, 0, stream>>>(aout, WoT, d_out, flags);
}

// Round 17
// 118.072 us; speedup vs baseline: 1.2300x; 1.0137x over previous
//
#include <hip/hip_runtime.h>

using u16 = unsigned short;
using uch = unsigned char;

typedef __bf16 bf16x8 __attribute__((ext_vector_type(8)));
typedef float f32x4 __attribute__((ext_vector_type(4)));

// ---------- constants ----------
#define BATCH 4
#define SEQN 4096
#define TT 16
#define MM 64
#define DIM 1024
#define HEADS 8
#define DH 64
#define INNER 512
#define KVN 1024
#define NTOK (BATCH*SEQN)          // 16384
#define MAXBLK 352

// front_kernel role boundaries (256-thread blocks)
#define FB_WT0  1
#define FB_CVT0 2049
#define FB_LN0  6145
#define FB_GRID (FB_LN0 + NTOK)    // 22529

// ws offsets (bytes)
#define OFF_XN     ((size_t)0)                     // 16384x1024 bf16 = 32MB
#define OFF_MEDIA  ((size_t)33554432)              // 4096x1024 bf16 = 8MB
#define OFF_Q      ((size_t)41943040)              // 16384x512 bf16 = 16MB
#define OFF_KV     ((size_t)58720256)              // 4096x1024 bf16 = 8MB
#define OFF_AOUT   ((size_t)67108864)              // 16384x512 bf16 = 16MB
#define OFF_WQT    ((size_t)83886080)              // 512x1024 bf16 = 1MB
#define OFF_WKVT   ((size_t)84934656)              // 1024x1024 bf16 = 2MB
#define OFF_WOT    ((size_t)87031808)              // 1024x512 bf16 = 1MB
#define OFF_VSUM   ((size_t)88145920)              // 4x512 f32 = 8KB
#define OFF_FLAGS  ((size_t)88154112)              // int[2]
#define OFF_VT     ((size_t)88155136)              // 64 groups x 512 x 64 bf16 = 4MB
#define OFF_NBLK   ((size_t)92350464)              // int
#define OFF_DESC   ((size_t)92351488)              // MAXBLK x int4

__device__ __forceinline__ u16 f2bf(float f){
  unsigned int u = __float_as_uint(f);
  u += 0x7fffu + ((u >> 16) & 1u);
  return (u16)(u >> 16);
}
__device__ __forceinline__ float bf2f(u16 b){ return __uint_as_float(((unsigned int)b) << 16); }

__device__ __forceinline__ void async16(const u16* g, void* l){
  __builtin_amdgcn_global_load_lds((__attribute__((address_space(1))) void*)(g),
                                   (__attribute__((address_space(3))) void*)(l), 16, 0, 0);
}

// per-block dtype probe on x[0..1023] words (4KB, valid under fp32 or bf16 layout).
__device__ __forceinline__ int detect_bf16(const unsigned int* __restrict__ x){
  __shared__ int scnt;
  const int tid = threadIdx.x;
  if (tid == 0) scnt = 0;
  __syncthreads();
  int c = 0;
  #pragma unroll
  for (int t = 0; t < 4; ++t){
    unsigned int w = x[t*256 + tid];
    unsigned int e = (w >> 7) & 0xFFu;
    c += (e >= 110u && e <= 140u) ? 1 : 0;
  }
  #pragma unroll
  for (int o = 32; o > 0; o >>= 1) c += __shfl_down(c, o);
  if ((tid & 63) == 0) atomicAdd(&scnt, c);
  __syncthreads();
  return scnt > 512 ? 1 : 0;
}

// ---------- front: prep + weight transposes + LN + media cvt (ONE dispatch) ----------
__global__ __launch_bounds__(256) void front_kernel(
    const unsigned int* __restrict__ x, const uch* __restrict__ loc,
    const void* __restrict__ ln_g, const void* __restrict__ ln_b,
    const void* __restrict__ media,
    const void* __restrict__ Wq, const void* __restrict__ Wk,
    const void* __restrict__ Wv, const void* __restrict__ Wo,
    u16* __restrict__ xn, u16* __restrict__ medb,
    u16* __restrict__ WqT, u16* __restrict__ WkvT, u16* __restrict__ WoT,
    int* __restrict__ flags, float* __restrict__ vsum,
    int4* __restrict__ desc, int* __restrict__ nblk){
  const int bid = blockIdx.x, tid = threadIdx.x;

  if (bid == 0){
    // ---- prep: loc-format probe, vsum zero, cumsum->bounds, plan ----
    __shared__ int nonzS;
    __shared__ int wsumS[4];
    __shared__ int sbound[4][19];
    __shared__ int gcnt[72];
    int bf = detect_bf16(x);
    if (tid == 0) nonzS = 0;
    if (tid < 76) sbound[tid/19][tid%19] = 4096;
    #pragma unroll
    for (int t = 0; t < 8; ++t) vsum[t*256 + tid] = 0.f;
    __syncthreads();
    int nz = 0;
    #pragma unroll
    for (int t = 0; t < 16; ++t){
      int i = t*256 + tid;                 // first 16KB valid in both layouts
      if ((i & 3) && loc[i]) nz++;
    }
    #pragma unroll
    for (int o = 32; o > 0; o >>= 1) nz += __shfl_down(nz, o);
    if ((tid & 63) == 0) atomicAdd(&nonzS, nz);
    __syncthreads();
    const int as32 = (nonzS == 0) ? 1 : 0;
    if (tid == 0){ flags[0] = bf; flags[1] = as32; }
    const int lane = tid & 63, wl = tid >> 6;
    for (int b = 0; b < BATCH; ++b){
      int v[16];
      if (as32){
        const int4* p = (const int4*)((const int*)loc + b*SEQN + tid*16);
        #pragma unroll
        for (int j = 0; j < 4; ++j){
          int4 q = p[j];
          v[j*4+0]=q.x!=0; v[j*4+1]=q.y!=0; v[j*4+2]=q.z!=0; v[j*4+3]=q.w!=0;
        }
      } else {
        const uchar4* p = (const uchar4*)(loc + b*SEQN + tid*16);
        #pragma unroll
        for (int j = 0; j < 4; ++j){
          uchar4 q = p[j];
          v[j*4+0]=q.x!=0; v[j*4+1]=q.y!=0; v[j*4+2]=q.z!=0; v[j*4+3]=q.w!=0;
        }
      }
      int tsum = 0;
      #pragma unroll
      for (int j = 0; j < 16; ++j) tsum += v[j];
      int s = tsum;
      #pragma unroll
      for (int o = 1; o < 64; o <<= 1){ int n2 = __shfl_up(s, o); if (lane >= o) s += n2; }
      if (lane == 63) wsumS[wl] = s;
      __syncthreads();
      int base = 0;
      for (int w2 = 0; w2 < wl; ++w2) base += wsumS[w2];
      int tt = base + s - tsum;            // exclusive prefix before my 16 tokens
      #pragma unroll
      for (int j = 0; j < 16; ++j){
        if (v[j]){ tt++; if (tt <= 17) sbound[b][tt] = tid*16 + j; }
      }
      __syncthreads();
    }
    if (tid < 72){
      int bb = tid/18, g = tid%18;
      int lo = (g == 0) ? 0 : sbound[bb][g];
      int hi = (g < 17) ? sbound[bb][g+1] : 4096;
      if (hi < lo) hi = lo;
      gcnt[tid] = (hi - lo + 63) >> 6;
    }
    __syncthreads();
    if (tid == 0){
      int acc = 0;
      for (int i = 0; i < 72; ++i){ int c2 = gcnt[i]; gcnt[i] = acc; acc += c2; }
      *nblk = acc;
    }
    __syncthreads();
    if (tid < 72){
      int bb = tid/18, g = tid%18;
      int lo = (g == 0) ? 0 : sbound[bb][g];
      int hi = (g < 17) ? sbound[bb][g+1] : 4096;
      if (hi < lo) hi = lo;
      int s2 = (g == 0 || g == 17) ? -1 : (g - 1);
      int n0 = gcnt[tid];
      for (int k = lo, j = 0; k < hi; k += 64, ++j){
        int4 d; d.x = bb; d.y = s2; d.z = bb*4096 + k; d.w = min(64, hi - k);
        desc[n0 + j] = d;
      }
    }
    return;
  }

  if (bid < FB_CVT0){
    // ---- weight transpose: in [K][N] -> out [N][K] bf16 ----
    const int bf = detect_bf16(x);
    __shared__ float tile[32][33];
    int id = bid - FB_WT0;
    const void* in; u16* out; int K, N, bx, by;
    if (id < 512){       in = Wq; out = WqT;  K = DIM;   N = INNER; bx = id & 15; by = id >> 4; }
    else if (id < 1024){ in = Wk; out = WkvT; K = DIM;   N = INNER; int l = id - 512;  bx = l & 15; by = l >> 4; }
    else if (id < 1536){ in = Wv; out = WkvT + (size_t)512*1024; K = DIM; N = INNER; int l = id - 1024; bx = l & 15; by = l >> 4; }
    else {               in = Wo; out = WoT;  K = INNER; N = DIM;   int l = id - 1536; bx = l & 31; by = l >> 5; }
    int n0 = bx*32, k0 = by*32;
    int tx = tid & 31, ty = tid >> 5;
    #pragma unroll
    for (int i = 0; i < 4; ++i){
      size_t idx = (size_t)(k0 + ty + i*8)*N + n0 + tx;
      tile[ty + i*8][tx] = bf ? bf2f(((const u16*)in)[idx]) : ((const float*)in)[idx];
    }
    __syncthreads();
    #pragma unroll
    for (int i = 0; i < 4; ++i)
      out[(size_t)(n0 + ty + i*8)*K + k0 + tx] = f2bf(tile[tx][ty + i*8]);
    return;
  }

  if (bid < FB_LN0){
    // ---- media convert ----
    const int bf = detect_bf16(x);
    size_t i = (size_t)(bid - FB_CVT0)*256 + tid;
    if (bf){
      ((ushort4*)medb)[i] = ((const ushort4*)media)[i];
    } else {
      float4 t = ((const float4*)media)[i];
      ushort4 o; o.x = f2bf(t.x); o.y = f2bf(t.y); o.z = f2bf(t.z); o.w = f2bf(t.w);
      ((ushort4*)medb)[i] = o;
    }
    return;
  }

  // ---- LayerNorm row ----
  const int bf = detect_bf16(x);
  const int row = bid - FB_LN0;
  float v[4];
  if (bf){
    ushort4 t = ((const ushort4*)((const u16*)x + (size_t)row*DIM))[tid];
    v[0]=bf2f(t.x); v[1]=bf2f(t.y); v[2]=bf2f(t.z); v[3]=bf2f(t.w);
  } else {
    float4 t = ((const float4*)((const float*)x + (size_t)row*DIM))[tid];
    v[0]=t.x; v[1]=t.y; v[2]=t.z; v[3]=t.w;
  }
  float s = v[0]+v[1]+v[2]+v[3];
  float sq = v[0]*v[0]+v[1]*v[1]+v[2]*v[2]+v[3]*v[3];
  #pragma unroll
  for (int o = 32; o > 0; o >>= 1){ s += __shfl_down(s, o); sq += __shfl_down(sq, o); }
  __shared__ float ss[4], ssq[4];
  int wid = tid >> 6, lane = tid & 63;
  if (lane == 0){ ss[wid] = s; ssq[wid] = sq; }
  __syncthreads();
  s = ss[0]+ss[1]+ss[2]+ss[3]; sq = ssq[0]+ssq[1]+ssq[2]+ssq[3];
  float mean = s * (1.f/DIM);
  float rstd = rsqrtf(sq * (1.f/DIM) - mean*mean + 1e-5f);
  float g[4], bb[4];
  if (bf){
    ushort4 t1 = ((const ushort4*)ln_g)[tid]; ushort4 t2 = ((const ushort4*)ln_b)[tid];
    g[0]=bf2f(t1.x); g[1]=bf2f(t1.y); g[2]=bf2f(t1.z); g[3]=bf2f(t1.w);
    bb[0]=bf2f(t2.x); bb[1]=bf2f(t2.y); bb[2]=bf2f(t2.z); bb[3]=bf2f(t2.w);
  } else {
    float4 t1 = ((const float4*)ln_g)[tid]; float4 t2 = ((const float4*)ln_b)[tid];
    g[0]=t1.x; g[1]=t1.y; g[2]=t1.z; g[3]=t1.w;
    bb[0]=t2.x; bb[1]=t2.y; bb[2]=t2.z; bb[3]=t2.w;
  }
  ushort4 o;
  o.x = f2bf((v[0]-mean)*rstd*g[0] + bb[0]);
  o.y = f2bf((v[1]-mean)*rstd*g[1] + bb[1]);
  o.z = f2bf((v[2]-mean)*rstd*g[2] + bb[2]);
  o.w = f2bf((v[3]-mean)*rstd*g[3] + bb[3]);
  ((ushort4*)(xn + (size_t)row*DIM))[tid] = o;
}

// ---------- 128^2 dbuf GEMM body; SYNC=0: syncthreads flip (r12), SYNC=1: counted vmcnt (r16) ----------
__device__ __forceinline__ void stage128(const u16* __restrict__ Ab, const u16* __restrict__ Bb,
                                         int K, int k0, u16* As, u16* Bs, int tid, int wid){
  #pragma unroll
  for (int t = 0; t < 4; ++t){
    int c = t*256 + tid;
    int row = c >> 3;
    int qs = (c & 7) ^ (row & 7);
    int ldsOff = (t*256 + wid*64) * 16;
    async16(Ab + (size_t)row*K + k0 + qs*8, (char*)As + ldsOff);
    async16(Bb + (size_t)row*K + k0 + qs*8, (char*)Bs + ldsOff);
  }
}

// MODE 0: C bf16 (alpha).  MODE 1: C bf16 if flags[0] else fp32.  MODE 2: kv epilogue.
template<int MODE, int SYNC>
__device__ __forceinline__ void gemm128_body(const u16* __restrict__ A, const u16* __restrict__ Bt,
                        void* __restrict__ Cp, int Nglob, int K, float alpha, int rm, int rn,
                        u16* As0, u16* As1, u16* Bs0, u16* Bs1,
                        u16* __restrict__ vtp, float* __restrict__ vsum,
                        const int* __restrict__ flags){
  const int tid = threadIdx.x, wid = tid >> 6, lane = tid & 63;
  const int wr = wid >> 1, wc = wid & 1;
  const int lr = lane & 15, lg = lane >> 4;
  f32x4 acc[4][4] = {};
  const u16* Ab = A + (size_t)rm*128*K;
  const u16* Bb = Bt + (size_t)rn*128*K;
  const int NT = K >> 6;

  stage128(Ab, Bb, K, 0, As0, Bs0, tid, wid);
  if (SYNC == 0) __syncthreads();                  // r12: tile 0 resident
  for (int t = 0; t < NT; ++t){
    u16* Ac = (t & 1) ? As1 : As0;
    u16* Bc = (t & 1) ? Bs1 : Bs0;
    u16* An = (t & 1) ? As0 : As1;
    u16* Bn = (t & 1) ? Bs0 : Bs1;
    if (SYNC == 1){
      if (t + 1 < NT){
        stage128(Ab, Bb, K, (t+1)*64, An, Bn, tid, wid);
        asm volatile("s_waitcnt vmcnt(8)" ::: "memory");
      } else {
        asm volatile("s_waitcnt vmcnt(0)" ::: "memory");
      }
      __builtin_amdgcn_s_barrier();                // tile t resident for all waves
      __builtin_amdgcn_sched_barrier(0);           // no ds_read hoists above the wait
    } else {
      if (t + 1 < NT)                              // r12: issue next-tile loads BEFORE compute
        stage128(Ab, Bb, K, (t+1)*64, An, Bn, tid, wid);
    }
    #pragma unroll
    for (int ks = 0; ks < 2; ++ks){
      bf16x8 af[4], bfr[4];
      #pragma unroll
      for (int m = 0; m < 4; ++m){
        int row = wr*64 + m*16 + lr;
        int q = (ks*4 + lg) ^ (row & 7);
        af[m] = *(const bf16x8*)((const char*)Ac + row*128 + (q << 4));
      }
      #pragma unroll
      for (int n = 0; n < 4; ++n){
        int row = wc*64 + n*16 + lr;
        int q = (ks*4 + lg) ^ (row & 7);
        bfr[n] = *(const bf16x8*)((const char*)Bc + row*128 + (q << 4));
      }
      #pragma unroll
      for (int m = 0; m < 4; ++m)
        #pragma unroll
        for (int n = 0; n < 4; ++n)
          acc[m][n] = __builtin_amdgcn_mfma_f32_16x16x32_bf16(af[m], bfr[n], acc[m][n], 0, 0, 0);
    }
    if (SYNC == 1) __builtin_amdgcn_s_barrier();   // all waves done reading cur buf
    else           __syncthreads();                // r12: next tile resident; cur buf free
  }
  if (MODE == 2){
    const int batch = rm >> 3;             // 8 row-tiles of 128 per batch (1024 rows)
    #pragma unroll
    for (int n = 0; n < 4; ++n){
      int col = rn*128 + wc*64 + n*16 + lr;
      float psum = 0.f;
      #pragma unroll
      for (int m = 0; m < 4; ++m){
        int row0 = rm*128 + wr*64 + m*16 + lg*4;
        #pragma unroll
        for (int r = 0; r < 4; ++r){
          float v = acc[m][n][r];
          psum += v;
          int row = row0 + r;
          u16 bv = f2bf(v);
          ((u16*)Cp)[(size_t)row*Nglob + col] = bv;
          if (col >= 512){
            int kvi = row & 1023;
            int s = kvi >> 6, rr = kvi & 63;
            vtp[((size_t)(((row >> 10)*16 + s)*512 + (col - 512)))*64 + rr] = bv;
          }
        }
      }
      if (col >= 512) atomicAdd(&vsum[batch*512 + (col - 512)], psum);
    }
  } else if (MODE == 1){
    const bool obf = flags[0] != 0;
    #pragma unroll
    for (int m = 0; m < 4; ++m){
      #pragma unroll
      for (int n = 0; n < 4; ++n){
        int row0 = rm*128 + wr*64 + m*16 + lg*4;
        int col  = rn*128 + wc*64 + n*16 + lr;
        #pragma unroll
        for (int r = 0; r < 4; ++r){
          float v = acc[m][n][r];
          size_t idx = (size_t)(row0 + r)*Nglob + col;
          if (obf) ((u16*)Cp)[idx] = f2bf(v);
          else     ((float*)Cp)[idx] = v;
        }
      }
    }
  } else {
    #pragma unroll
    for (int m = 0; m < 4; ++m){
      #pragma unroll
      for (int n = 0; n < 4; ++n){
        int row0 = rm*128 + wr*64 + m*16 + lg*4;
        int col  = rn*128 + wc*64 + n*16 + lr;
        #pragma unroll
        for (int r = 0; r < 4; ++r)
          ((u16*)Cp)[(size_t)(row0 + r)*Nglob + col] = f2bf(acc[m][n][r] * alpha);
      }
    }
  }
}

// ---------- proj: q-proj (blocks 0..511) + kv-proj (blocks 512..767), r12 schedule ----------
__global__ __launch_bounds__(256) void proj_kernel(
    const u16* __restrict__ xn, const u16* __restrict__ WqT, u16* __restrict__ qb,
    const u16* __restrict__ medb, const u16* __restrict__ WkvT, u16* __restrict__ kvb,
    u16* __restrict__ vtp, float* __restrict__ vsum){
  __shared__ u16 As[2][128*64];
  __shared__ u16 Bs[2][128*64];
  if (blockIdx.x < 512){
    // q = (xn @ Wq) * DH^-0.5 : M=16384 (128 tiles) x N=512 (4 tiles)
    int bid = blockIdx.x;
    int wg = (bid & 7)*64 + (bid >> 3);
    gemm128_body<0, 0>(xn, WqT, qb, INNER, DIM, 0.125f, wg >> 2, wg & 3,
                       As[0], As[1], Bs[0], Bs[1], nullptr, nullptr, nullptr);
  } else {
    // kv = media @ [Wk|Wv] : M=4096 (32 tiles) x N=1024 (8 tiles)
    int bid = blockIdx.x - 512;
    int wg = (bid & 7)*32 + (bid >> 3);
    gemm128_body<2, 0>(medb, WkvT, kvb, 1024, DIM, 1.f, wg >> 3, wg & 7,
                       As[0], As[1], Bs[0], Bs[1], vtp, vsum, nullptr);
  }
}

// ---------- out = aout @ Wo : counted-vmcnt schedule (r16's best half), 1024 blocks ----------
__global__ __launch_bounds__(256) void gemm_out_kernel(const u16* __restrict__ A,
                        const u16* __restrict__ Bt, void* __restrict__ Cp,
                        const int* __restrict__ flags){
  __shared__ u16 As[2][128*64];
  __shared__ u16 Bs[2][128*64];
  int bid = blockIdx.x;
  int wg = (bid & 7)*128 + (bid >> 3);
  gemm128_body<1, 1>(A, Bt, Cp, DIM, INNER, 1.f, wg >> 3, wg & 7,
                     As[0], As[1], Bs[0], Bs[1], nullptr, nullptr, flags);
}

// ---------- grouped masked attention: 1 head per block ----------
__global__ __launch_bounds__(256) void attn2_kernel(
    const u16* __restrict__ qb, const u16* __restrict__ kvb, const u16* __restrict__ vt,
    const int* __restrict__ nblk, const int4* __restrict__ desc,
    const float* __restrict__ vsum, u16* __restrict__ aout){
  __shared__ u16 Ks[64*64];
  __shared__ u16 Vs[64*64];
  __shared__ u16 Ps[4][16*72];
  if (blockIdx.x >= *nblk) return;
  const int4 d = desc[blockIdx.x];
  const int b = d.x, s = d.y, rowStart = d.z, cnt = d.w;
  const int h = blockIdx.y;
  const int tid = threadIdx.x, w = tid >> 6, lane = tid & 63;
  if (s < 0){
    const float inv = 1.f/1024.f;
    for (int idx = tid; idx < cnt*64; idx += 256){
      int slot = idx >> 6, c = h*64 + (idx & 63);
      aout[(size_t)(rowStart + slot)*512 + c] = f2bf(vsum[b*512 + c]*inv);
    }
    return;
  }
  const int lr = lane & 15, lg = lane >> 4;
  const size_t kbase = ((size_t)(b*1024 + s*64))*1024;
  const size_t vbase = ((size_t)(b*16 + s))*512*64;
  const int myslot = w*16 + lr;
  const size_t qrow = (size_t)(rowStart + min(myslot, cnt - 1))*512;
  #pragma unroll
  for (int t = 0; t < 2; ++t){
    int ci = t*256 + tid;
    int r = ci >> 3, q = ci & 7;
    int qs = (q ^ (r & 7)) << 3;
    async16(kvb + kbase + (size_t)r*1024 + h*64 + qs, (char*)Ks + ci*16);
    async16(vt + vbase + (size_t)(h*64 + r)*64 + qs, (char*)Vs + ci*16);
  }
  __syncthreads();
  bf16x8 qa0 = *(const bf16x8*)(qb + qrow + h*64 + lg*8);
  bf16x8 qa1 = *(const bf16x8*)(qb + qrow + h*64 + 32 + lg*8);
  f32x4 sv[4] = {};
  #pragma unroll
  for (int n = 0; n < 4; ++n){
    int row = n*16 + lr;
    int sl0 = (lg) ^ (row & 7);
    int sl1 = (4 + lg) ^ (row & 7);
    bf16x8 kb0 = *(const bf16x8*)((const char*)Ks + row*128 + sl0*16);
    sv[n] = __builtin_amdgcn_mfma_f32_16x16x32_bf16(qa0, kb0, sv[n], 0, 0, 0);
    bf16x8 kb1 = *(const bf16x8*)((const char*)Ks + row*128 + sl1*16);
    sv[n] = __builtin_amdgcn_mfma_f32_16x16x32_bf16(qa1, kb1, sv[n], 0, 0, 0);
  }
  float inv[4];
  #pragma unroll
  for (int r = 0; r < 4; ++r){
    float m = fmaxf(fmaxf(sv[0][r], sv[1][r]), fmaxf(sv[2][r], sv[3][r]));
    #pragma unroll
    for (int o = 1; o < 16; o <<= 1) m = fmaxf(m, __shfl_xor(m, o));
    float s0 = 0.f;
    #pragma unroll
    for (int n = 0; n < 4; ++n){ sv[n][r] = __expf(sv[n][r] - m); s0 += sv[n][r]; }
    #pragma unroll
    for (int o = 1; o < 16; o <<= 1) s0 += __shfl_xor(s0, o);
    inv[r] = 1.f / s0;
  }
  u16* pw = &Ps[w][0];
  #pragma unroll
  for (int n = 0; n < 4; ++n)
    #pragma unroll
    for (int r = 0; r < 4; ++r)
      pw[(4*lg + r)*72 + n*16 + lr] = f2bf(sv[n][r] * inv[r]);
  bf16x8 pa0 = *(const bf16x8*)((const char*)pw + lr*144 + lg*16);
  bf16x8 pa1 = *(const bf16x8*)((const char*)pw + lr*144 + 64 + lg*16);
  f32x4 ov[4] = {};
  #pragma unroll
  for (int n = 0; n < 4; ++n){
    int row = n*16 + lr;
    int sl0 = (lg) ^ (row & 7);
    int sl1 = (4 + lg) ^ (row & 7);
    bf16x8 vb0 = *(const bf16x8*)((const char*)Vs + row*128 + sl0*16);
    ov[n] = __builtin_amdgcn_mfma_f32_16x16x32_bf16(pa0, vb0, ov[n], 0, 0, 0);
    bf16x8 vb1 = *(const bf16x8*)((const char*)Vs + row*128 + sl1*16);
    ov[n] = __builtin_amdgcn_mfma_f32_16x16x32_bf16(pa1, vb1, ov[n], 0, 0, 0);
  }
  #pragma unroll
  for (int r = 0; r < 4; ++r){
    int slot = w*16 + 4*lg + r;
    if (slot < cnt){
      size_t orow = (size_t)(rowStart + slot)*512 + h*64;
      #pragma unroll
      for (int n = 0; n < 4; ++n)
        aout[orow + n*16 + lr] = f2bf(ov[n][r]);
    }
  }
}

extern "C" void kernel_launch(void* const* d_in, const int* in_sizes, int n_in,
                              void* d_out, int out_size, void* d_ws, size_t ws_size,
                              hipStream_t stream){
  const void* x      = d_in[0];
  const void* media  = d_in[1];
  const void* mloc   = d_in[2];
  const void* ln_g   = d_in[3];
  const void* ln_b   = d_in[4];
  const void* Wq     = d_in[5];
  const void* Wk     = d_in[6];
  const void* Wv     = d_in[7];
  const void* Wo     = d_in[8];
  char* ws = (char*)d_ws;
  u16* xn    = (u16*)(ws + OFF_XN);
  u16* medb  = (u16*)(ws + OFF_MEDIA);
  u16* qb    = (u16*)(ws + OFF_Q);
  u16* kvb   = (u16*)(ws + OFF_KV);
  u16* aout  = (u16*)(ws + OFF_AOUT);
  u16* WqT   = (u16*)(ws + OFF_WQT);
  u16* WkvT  = (u16*)(ws + OFF_WKVT);
  u16* WoT   = (u16*)(ws + OFF_WOT);
  float* vsm = (float*)(ws + OFF_VSUM);
  int* flags = (int*)(ws + OFF_FLAGS);
  u16* vt    = (u16*)(ws + OFF_VT);
  int* nblk  = (int*)(ws + OFF_NBLK);
  int4* desc = (int4*)(ws + OFF_DESC);

  // 1) prep + weight transposes + LN + media cvt
  front_kernel<<<FB_GRID, 256, 0, stream>>>(
      (const unsigned int*)x, (const uch*)mloc, ln_g, ln_b, media,
      Wq, Wk, Wv, Wo, xn, medb, WqT, WkvT, WoT, flags, vsm, desc, nblk);

  // 2) q-proj + kv-proj, r12 syncthreads-dbuf schedule (best measured: 49 us)
  proj_kernel<<<768, 256, 0, stream>>>(xn, WqT, qb, medb, WkvT, kvb, vt, vsm);

  // 3) grouped masked attention
  attn2_kernel<<<dim3(MAXBLK, 8), 256, 0, stream>>>(qb, kvb, vt, nblk, desc, vsm, aout);

  // 4) out-proj, counted-vmcnt schedule (r16's best half), 1024 blocks
  gemm_out_kernel<<<1024, 256, 0, stream>>>(aout, WoT, d_out, flags);
}